// Round 3
// baseline (1191.525 us; speedup 1.0000x reference)
//
#include <hip/hip_runtime.h>

#define NBATCH 64
#define SRCLEN 2048
#define DIMK 1024
#define MROWS (NBATCH * SRCLEN) /* 131072 */
#define NNB 4                   /* n-blocks of 256 */

typedef __attribute__((ext_vector_type(4))) float f32x4;
typedef __attribute__((ext_vector_type(8))) short bf16x8;

#define AS_GLOBAL __attribute__((address_space(1)))
#define AS_LDS __attribute__((address_space(3)))

__device__ __forceinline__ int cvt_pk_bf16(float a, float b) {
#if __has_builtin(__builtin_amdgcn_cvt_pk_bf16_f32)
  auto p = __builtin_amdgcn_cvt_pk_bf16_f32(a, b);
  return __builtin_bit_cast(int, p);
#else
  unsigned ua = __float_as_uint(a), ub = __float_as_uint(b);
  ua = (ua + 0x7fffu + ((ua >> 16) & 1u)) >> 16;
  ub = (ub + 0x7fffu + ((ub >> 16) & 1u)) & 0xffff0000u;
  return (int)(ua | ub);
#endif
}

__device__ __forceinline__ float fast_tanh(float x) {
#if __has_builtin(__builtin_amdgcn_exp2f) && __has_builtin(__builtin_amdgcn_rcpf)
  float e = __builtin_amdgcn_exp2f(x * 2.885390081777927f);
  return 1.0f - 2.0f * __builtin_amdgcn_rcpf(e + 1.0f);
#else
  float cx = fminf(15.f, fmaxf(-15.f, x));
  float e = __expf(2.0f * cx);
  return (e - 1.0f) / (e + 1.0f);
#endif
}

// ---------------- K0a: W_context fp32 -> bf16 (row-major [n][k]) ----------------
__global__ __launch_bounds__(256) void cvt_wc_kernel(const float* __restrict__ W,
                                                     unsigned short* __restrict__ Wb) {
  int i = (blockIdx.x * 256 + threadIdx.x) * 4;
  f32x4 x = *(const f32x4*)(W + i);
  int2 o;
  o.x = cvt_pk_bf16(x[0], x[1]);
  o.y = cvt_pk_bf16(x[2], x[3]);
  *(int2*)(Wb + i) = o;
}

// ---------------- K0b: bias[b][n] = src@Wq^T + cond@Wcd^T + bq ----------------
__global__ __launch_bounds__(256) void bias_kernel(
    const float* __restrict__ src, const float* __restrict__ cond,
    const float* __restrict__ Wq, const float* __restrict__ bq,
    const float* __restrict__ Wcd, float* __restrict__ biasOut) {
  const int b = blockIdx.y, nb = blockIdx.x, tid = threadIdx.x;
  const int w = tid >> 6, lane = tid & 63;
  __shared__ float sl[1024], cl[1024];
  *(f32x4*)(sl + (tid << 2)) = *(const f32x4*)(src + (b << 10) + (tid << 2));
  *(f32x4*)(cl + (tid << 2)) = *(const f32x4*)(cond + (b << 10) + (tid << 2));
  __syncthreads();
  f32x4 s4[4], c4[4];
#pragma unroll
  for (int u = 0; u < 4; ++u) {
    s4[u] = *(const f32x4*)(sl + (lane << 4) + (u << 2));
    c4[u] = *(const f32x4*)(cl + (lane << 4) + (u << 2));
  }
  for (int it = 0; it < 32; ++it) {
    const int n = (nb << 7) + (w << 5) + it;
    const float* wq = Wq + (size_t)n * DIMK + (lane << 4);
    const float* wc = Wcd + (size_t)n * DIMK + (lane << 4);
    float a = 0.f;
#pragma unroll
    for (int u = 0; u < 4; ++u) {
      f32x4 q4 = *(const f32x4*)(wq + (u << 2));
      f32x4 w4 = *(const f32x4*)(wc + (u << 2));
      a += q4[0] * s4[u][0] + q4[1] * s4[u][1] + q4[2] * s4[u][2] + q4[3] * s4[u][3];
      a += w4[0] * c4[u][0] + w4[1] * c4[u][1] + w4[2] * c4[u][2] + w4[3] * c4[u][3];
    }
#pragma unroll
    for (int xm = 1; xm < 64; xm <<= 1) a += __shfl_xor(a, xm, 64);
    if (lane == 0) biasOut[(b << 10) + n] = a + bq[n];
  }
}

// ---------------- KB: fused GEMM + tanh + v-dot -> align partials ----------------
// 512 threads, tile 128m x 256n, BK=32, 8 waves (2m x 4n) each 64x64 (acc 4x4).
// A: fp32 global -> regs -> cvt bf16 -> LDS (8 KiB). B: bf16 DMA (16 KiB).
// Swizzle: 16B chunk c of row r stored at c ^ ((r>>1)&3). Frag reads are 2-way (free).
__global__ __launch_bounds__(512, 4) void gemm_align_kernel(
    const float* __restrict__ mb, const unsigned short* __restrict__ Wc,
    const float* __restrict__ bias, const float* __restrict__ v,
    float* __restrict__ alignPt) {
  __shared__ unsigned short As[128 * 32];  // 8 KiB
  __shared__ unsigned short Bs[256 * 32];  // 16 KiB
  __shared__ float red[4][128];            // 2 KiB

  const int tid = threadIdx.x;
  const int lane = tid & 63;
  const int w = tid >> 6;
  const int wm = w & 1, wn = w >> 1;
  const int lr = lane & 15, quad = lane >> 4;
  const int nb = blockIdx.x;
  const int m0 = blockIdx.y << 7;
  const int n0 = nb << 8;

  // ---- A staging constants (thread t covers rows u*64+(t>>3), 32B of fp32) ----
  const int arow = tid >> 3;             // 0..63
  const int acol = (tid & 7) << 2;       // f32 col 0..28
  const float* gA = mb + (size_t)(m0 + arow) * DIMK + acol;
  const int ap = (((tid & 7) >> 1) ^ ((tid >> 4) & 3));  // swizzled chunk
  // LDS bf16 addr (elements): row*32 + p*8 + (t&1)*4
  unsigned short* aw0 = As + (arow << 5) + (ap << 3) + ((tid & 1) << 2);
  unsigned short* aw1 = aw0 + (64 << 5);

  // ---- B staging constants (wave issues q = w*2+r; 16 rows x 64B per DMA) ----
  const int brow0 = (w << 5) + (lane >> 2);            // q=w*2 row base + lane>>2
  const int bc = ((lane & 3) ^ ((lane >> 3) & 3));     // swizzled chunk (global side)
  const unsigned short* gB0 = Wc + (size_t)(n0 + brow0) * DIMK + (bc << 3);
  const unsigned short* gB1 = gB0 + (size_t)16 * DIMK;

  // ---- frag read addresses (kt-invariant) ----
  const int fsw = (quad ^ ((lr >> 1) & 3)) << 3;  // chunk*8 elements
  const unsigned short* ard = As + (((wm << 6) + lr) << 5) + fsw;
  const unsigned short* brd = Bs + (((wn << 6) + lr) << 5) + fsw;

  f32x4 acc[4][4] = {};

  for (int kt = 0; kt < 32; ++kt) {
    const int ko = kt << 5;
    // A: 2 x f32x4 loads per thread
    f32x4 xa0 = *(const f32x4*)(gA + ko);
    f32x4 xa1 = *(const f32x4*)(gA + (64 * DIMK) + ko);
    // B: 2 DMA issues per wave
    __builtin_amdgcn_global_load_lds((const AS_GLOBAL unsigned*)(gB0 + ko),
                                     (AS_LDS unsigned*)(Bs + (w << 10)), 16, 0, 0);
    __builtin_amdgcn_global_load_lds((const AS_GLOBAL unsigned*)(gB1 + ko),
                                     (AS_LDS unsigned*)(Bs + (w << 10) + 512), 16, 0, 0);
    __syncthreads();  // prev compute done; drains vmcnt (xa + B DMA)
    int2 o0, o1;
    o0.x = cvt_pk_bf16(xa0[0], xa0[1]);
    o0.y = cvt_pk_bf16(xa0[2], xa0[3]);
    o1.x = cvt_pk_bf16(xa1[0], xa1[1]);
    o1.y = cvt_pk_bf16(xa1[2], xa1[3]);
    *(int2*)aw0 = o0;
    *(int2*)aw1 = o1;
    __syncthreads();  // A writes visible

    bf16x8 af[4];
#pragma unroll
    for (int i = 0; i < 4; ++i) af[i] = *(const bf16x8*)(ard + (i << 9));
#pragma unroll
    for (int j = 0; j < 4; ++j) {
      bf16x8 bf = *(const bf16x8*)(brd + (j << 9));
#pragma unroll
      for (int i = 0; i < 4; ++i)
        acc[i][j] = __builtin_amdgcn_mfma_f32_16x16x32_bf16(af[i], bf, acc[i][j], 0, 0, 0);
    }
  }

  // Epilogue: t = tanh(acc + bias[b][n]); partial over this block's 256 n's
  const int b = m0 >> 11;
  float rowsum[4][4] = {};
#pragma unroll
  for (int j = 0; j < 4; ++j) {
    int n = n0 + (wn << 6) + (j << 4) + lr;  // C/D col = lane&15
    float bn = bias[(b << 10) + n];
    float vn = v[n];
#pragma unroll
    for (int i = 0; i < 4; ++i)
#pragma unroll
      for (int rg = 0; rg < 4; ++rg) {
        float t = fast_tanh(acc[i][j][rg] + bn);
        rowsum[i][rg] = fmaf(t, vn, rowsum[i][rg]);
      }
  }
#pragma unroll
  for (int xm = 1; xm < 16; xm <<= 1)
#pragma unroll
    for (int i = 0; i < 4; ++i)
#pragma unroll
      for (int rg = 0; rg < 4; ++rg)
        rowsum[i][rg] += __shfl_xor(rowsum[i][rg], xm, 64);
  if (lr == 0) {
#pragma unroll
    for (int i = 0; i < 4; ++i)
#pragma unroll
      for (int rg = 0; rg < 4; ++rg)
        red[wn][(wm << 6) + (i << 4) + (quad << 2) + rg] = rowsum[i][rg];
  }
  __syncthreads();
  if (tid < 128)
    alignPt[(size_t)(m0 + tid) * NNB + nb] =
        red[0][tid] + red[1][tid] + red[2][tid] + red[3][tid];
}

// ---------------- KC: softmax over s per batch; writes output 1 ----------------
__global__ __launch_bounds__(256) void softmax_kernel(const float* __restrict__ alignPt,
                                                      float* __restrict__ outA) {
  const int b = blockIdx.x, tid = threadIdx.x;
  float loc[8];
  float mx = -3.0e38f;
#pragma unroll
  for (int r = 0; r < 8; ++r) {
    int s = (r << 8) + tid;
    f32x4 p = *(const f32x4*)(alignPt + (size_t)((b << 11) + s) * NNB);
    float a = p[0] + p[1] + p[2] + p[3];
    loc[r] = a;
    mx = fmaxf(mx, a);
  }
#pragma unroll
  for (int o = 32; o > 0; o >>= 1) mx = fmaxf(mx, __shfl_xor(mx, o, 64));
  __shared__ float sred[8];
  if ((tid & 63) == 0) sred[tid >> 6] = mx;
  __syncthreads();
  mx = fmaxf(fmaxf(sred[0], sred[1]), fmaxf(sred[2], sred[3]));
  float sum = 0.f;
#pragma unroll
  for (int r = 0; r < 8; ++r) {
    loc[r] = __expf(loc[r] - mx);
    sum += loc[r];
  }
#pragma unroll
  for (int o = 32; o > 0; o >>= 1) sum += __shfl_xor(sum, o, 64);
  __syncthreads();
  if ((tid & 63) == 0) sred[4 + (tid >> 6)] = sum;
  __syncthreads();
  sum = sred[4] + sred[5] + sred[6] + sred[7];
  float inv = 1.0f / sum;
#pragma unroll
  for (int r = 0; r < 8; ++r) outA[(b << 11) + (r << 8) + tid] = loc[r] * inv;
}

// ---------------- KD: context partials c_chunk[b][d] = sum_s w*h ----------------
__global__ __launch_bounds__(256) void ctx_partial_kernel(const float* __restrict__ mb,
                                                          const float* __restrict__ wgt,
                                                          float* __restrict__ cP) {
  const int chunk = blockIdx.x, b = blockIdx.y, tid = threadIdx.x;
  __shared__ float wl[64];
  if (tid < 64) wl[tid] = wgt[(b << 11) + (chunk << 6) + tid];
  __syncthreads();
  const float* base = mb + ((size_t)(b << 11) + (chunk << 6)) * DIMK + (tid << 2);
  f32x4 a = {0.f, 0.f, 0.f, 0.f};
#pragma unroll 8
  for (int s = 0; s < 64; ++s) {
    f32x4 m4 = *(const f32x4*)(base + (size_t)s * DIMK);
    a += m4 * wl[s];
  }
  *(f32x4*)(cP + ((size_t)((chunk << 6) + b) << 10) + (tid << 2)) = a;
}

// ---------------- KE: reduce 32 chunks -> c (output 0) ----------------
__global__ __launch_bounds__(256) void ctx_reduce_kernel(const float* __restrict__ cP,
                                                         float* __restrict__ out) {
  int idx = blockIdx.x * 256 + threadIdx.x;
  float s = 0.f;
#pragma unroll
  for (int c = 0; c < 32; ++c) s += cP[(size_t)(c << 16) + idx];
  out[idx] = s;
}

extern "C" void kernel_launch(void* const* d_in, const int* in_sizes, int n_in,
                              void* d_out, int out_size, void* d_ws, size_t ws_size,
                              hipStream_t stream) {
  const float* source = (const float*)d_in[0];
  const float* mb = (const float*)d_in[1];
  const float* cond = (const float*)d_in[2];
  const float* Wq = (const float*)d_in[3];
  const float* bq = (const float*)d_in[4];
  const float* Wc = (const float*)d_in[5];
  const float* Wcd = (const float*)d_in[6];
  const float* v = (const float*)d_in[7];
  float* out = (float*)d_out;

  // ws: Wc_bf16 2 MiB | bias 256 KiB | alignPt 2 MiB | cP 8 MiB
  char* ws = (char*)d_ws;
  unsigned short* Wc_bf = (unsigned short*)ws;
  float* bias = (float*)(ws + (2u << 20));
  float* alignPt = (float*)(ws + (2u << 20) + (256u << 10));
  float* cP = (float*)(ws + (4u << 20) + (256u << 10));

  cvt_wc_kernel<<<1024, 256, 0, stream>>>(Wc, Wc_bf);
  bias_kernel<<<dim3(8, 64), 256, 0, stream>>>(source, cond, Wq, bq, Wcd, bias);
  gemm_align_kernel<<<dim3(NNB, 1024), 512, 0, stream>>>(mb, Wc_bf, bias, v, alignPt);
  softmax_kernel<<<64, 256, 0, stream>>>(alignPt, out + NBATCH * DIMK);
  ctx_partial_kernel<<<dim3(32, 64), 256, 0, stream>>>(mb, out + NBATCH * DIMK, cP);
  ctx_reduce_kernel<<<256, 256, 0, stream>>>(cP, out);
}